// Round 7
// baseline (345.659 us; speedup 1.0000x reference)
//
#include <hip/hip_runtime.h>
#include <hip/hip_bf16.h>

// LSTM B=8192,T=512,I=3,H=25 + linear[H->1], bf16 MFMA 16x16x32.
// R7: R5/R6 both hit 238us: per-block serial chain (barrier -> ds_read h ->
// MFMA -> trans chain -> ds_write -> drain -> barrier, ~600cy) is exposed and
// the 2 co-resident blocks phase-lock. Fix: interleave TWO 16-batch tiles in
// one 7-wave block; each wave computes frag T=w for both tiles alternately.
// Tile B's h(t) is visible at barrier#2(t-1) -> its ds_read issues at loop
// top and hides under tile A's compute; bfA(t+1) prefetched after barrier#1
// hides under tile B's compute. Latency hiding is intra-wave ILP, not
// scheduler luck. 256 blocks = exactly 1/CU (32/XCD).
// x pre-packed bf16 in LDS, 2 chunks of 256 steps (64 KB, 1 mid-loop restage).

#define TSTEPS 512
#define ISZ 3
#define HSZ 25
#define NW 7
#define CHUNK 256
#define TSTRIDE 40          // shorts per batch row (80 B)

typedef __attribute__((ext_vector_type(8))) short bf16x8;
typedef __attribute__((ext_vector_type(4))) float f32x4;

__device__ __forceinline__ unsigned short bf16_bits(float v) {
    return __builtin_bit_cast(unsigned short, __float2bfloat16(v));
}
__device__ __forceinline__ unsigned int pack_bf16(float lo, float hi) {
    return ((unsigned int)bf16_bits(hi) << 16) | (unsigned int)bf16_bits(lo);
}

// 8-trans LSTM cell: c' = sig(a1)*c + sig(a0)*tanh(a2); h = sig(a3)*tanh(c')
__device__ __forceinline__ void lstm_act(const f32x4 acc, float& c, float& h) {
    const float K1 = 1.442695040888963f;   // log2 e
    const float K2 = 2.885390081777927f;   // 2 log2 e
    const float e0 = __builtin_amdgcn_exp2f(-K1 * acc[0]);
    const float e1 = __builtin_amdgcn_exp2f(-K1 * acc[1]);
    const float e2 = __builtin_amdgcn_exp2f(fminf(-K2 * acc[2], 126.0f));
    const float e3 = __builtin_amdgcn_exp2f(-K1 * acc[3]);
    const float f  = __builtin_amdgcn_rcpf(1.0f + e1);
    const float ig = (1.0f - e2) * __builtin_amdgcn_rcpf((1.0f + e0) * (1.0f + e2));
    c = fmaf(f, c, ig);
    const float ec = __builtin_amdgcn_exp2f(fminf(-K2 * c, 126.0f));
    h = (1.0f - ec) * __builtin_amdgcn_rcpf((1.0f + e3) * (1.0f + ec));
}

__global__ __launch_bounds__(NW * 64) void lstm_mfma(
    const float* __restrict__ x,      // [B, T, I]
    const float* __restrict__ w_ih,   // [4H, I]
    const float* __restrict__ w_hh,   // [4H, H]
    const float* __restrict__ b_ih,   // [4H]
    const float* __restrict__ b_hh,   // [4H]
    const float* __restrict__ w_lin,  // [1, H]
    const float* __restrict__ b_lin,  // [1]
    float* __restrict__ out)          // [B, 1]
{
    __shared__ uint2 xpk[2][CHUNK][16];       // 64 KB packed bf16 x (+1.0)
    __shared__ short hb[2][2][16 * TSTRIDE];  // [parity][tile] h rows, 5 KB
    __shared__ float outred[2][NW][16];

    const int tid  = threadIdx.x;
    const int w    = tid >> 6;       // wave 0..6: frag T=w (units 4w..4w+3)
    const int lane = tid & 63;
    const int n    = lane & 15;      // batch within tile
    const int q    = lane >> 4;      // quad -> unit u = 4w + q
    const bool isq0 = (q == 0);
    const int u    = 4 * w + q;
    const bool act = (w < 6) || isq0;          // u < 25

    // zero both h parity buffers, both tiles (pad slots stay 0 forever)
    for (int i = tid; i < 2 * 2 * 16 * TSTRIDE; i += NW * 64) ((short*)hb)[i] = 0;

    // ---- stage one 256-step chunk of x for both tiles (pre-packed bf16) ----
    auto stage = [&](int c0) {
        const int bsel = tid & 31;                 // batch in the 32-batch pair
        const int tile = bsel >> 4, nn = bsel & 15;
        const float* __restrict__ g =
            x + (size_t)(blockIdx.x * 32 + bsel) * (TSTEPS * ISZ) + c0 * ISZ;
        for (int tg = tid >> 5; tg < CHUNK / 4; tg += 14) {   // 4-step groups
            const float4* f4 = (const float4*)(g + tg * 12);
            float4 a = f4[0], b4 = f4[1], c4 = f4[2];
            const float s[4][3] = { {a.x, a.y, a.z}, {a.w, b4.x, b4.y},
                                    {b4.z, b4.w, c4.x}, {c4.y, c4.z, c4.w} };
            #pragma unroll
            for (int uu = 0; uu < 4; ++uu) {
                uint2 d;
                d.x = pack_bf16(s[uu][0], s[uu][1]);
                d.y = pack_bf16(s[uu][2], 1.0f);
                xpk[tile][tg * 4 + uu][nn] = d;
            }
        }
    };
    stage(0);

    // ---- this wave's A fragment (loaded once, register-resident) ----
    // A[r=16w+n][k=q*8+j]; row r=4u'+g (unit-major); k: [w_ih 0..2, bias 3, w_hh 4..28]
    bf16x8 afrag;
    #pragma unroll
    for (int j = 0; j < 8; ++j) {
        const int k = q * 8 + j;
        const int r = 16 * w + n;
        const int uu = r >> 2, g = r & 3;
        float v = 0.0f;
        if (uu < HSZ) {
            const int orow = g * HSZ + uu;         // original i,f,g,o row order
            if (k < ISZ)            v = w_ih[orow * ISZ + k];
            else if (k == ISZ)      v = b_ih[orow] + b_hh[orow];
            else if (k < 4 + HSZ)   v = w_hh[orow * HSZ + (k - 4)];
        }
        afrag[j] = (short)bf16_bits(v);
    }

    __syncthreads();

    float cA = 0.f, hA = 0.f, cB = 0.f, hB = 0.f;
    bf16x8 bfA = *reinterpret_cast<const bf16x8*>(&hb[0][0][n * TSTRIDE + q * 8]);

    #pragma unroll 1
    for (int t = 0; t < TSTEPS; ++t) {
        if (t == CHUNK) {                 // entry synced by barrier#2 of t-1
            stage(CHUNK);
            __syncthreads();
        }
        const int ts = t & (CHUNK - 1);
        const uint2 xA = xpk[0][ts][n];
        const uint2 xB = xpk[1][ts][n];
        // tile B's h(t): visible since barrier#2(t-1); latency hides under A
        bf16x8 bfB = *reinterpret_cast<const bf16x8*>(&hb[t & 1][1][n * TSTRIDE + q * 8]);

        // ---- tile A step ----
        {
            uint4 bi = __builtin_bit_cast(uint4, bfA);
            if (isq0) { bi.x = xA.x; bi.y = xA.y; }
            const f32x4 accA = __builtin_amdgcn_mfma_f32_16x16x32_bf16(
                afrag, __builtin_bit_cast(bf16x8, bi),
                (f32x4){0.f, 0.f, 0.f, 0.f}, 0, 0, 0);
            lstm_act(accA, cA, hA);
            if (act) hb[(t + 1) & 1][0][n * TSTRIDE + 4 + u] = (short)bf16_bits(hA);
        }
        __syncthreads();                  // barrier#1: hA(t+1) visible
        // prefetch next iteration's tile-A fragment; hides under B's compute
        bfA = *reinterpret_cast<const bf16x8*>(&hb[(t + 1) & 1][0][n * TSTRIDE + q * 8]);

        // ---- tile B step ----
        {
            uint4 bi = __builtin_bit_cast(uint4, bfB);
            if (isq0) { bi.x = xB.x; bi.y = xB.y; }
            const f32x4 accB = __builtin_amdgcn_mfma_f32_16x16x32_bf16(
                afrag, __builtin_bit_cast(bf16x8, bi),
                (f32x4){0.f, 0.f, 0.f, 0.f}, 0, 0, 0);
            lstm_act(accB, cB, hB);
            if (act) hb[(t + 1) & 1][1][n * TSTRIDE + 4 + u] = (short)bf16_bits(hB);
        }
        __syncthreads();                  // barrier#2: hB(t+1) visible
    }

    // ---- final linear: out[b] = sum_u w_lin[u]*h[u] + b_lin ----
    float vA = 0.f, vB = 0.f;
    if (act) { vA = w_lin[u] * hA; vB = w_lin[u] * hB; }
    vA += __shfl_xor(vA, 16); vA += __shfl_xor(vA, 32);
    vB += __shfl_xor(vB, 16); vB += __shfl_xor(vB, 32);
    if (lane < 16) { outred[0][w][lane] = vA; outred[1][w][lane] = vB; }
    __syncthreads();
    if (tid < 32) {
        const int tile = tid >> 4, nn = tid & 15;
        float s = b_lin[0];
        #pragma unroll
        for (int k = 0; k < NW; ++k) s += outred[tile][k][nn];
        out[blockIdx.x * 32 + tile * 16 + nn] = s;
    }
}

extern "C" void kernel_launch(void* const* d_in, const int* in_sizes, int n_in,
                              void* d_out, int out_size, void* d_ws, size_t ws_size,
                              hipStream_t stream) {
    const float* x     = (const float*)d_in[0];
    const float* w_ih  = (const float*)d_in[1];
    const float* w_hh  = (const float*)d_in[2];
    const float* b_ih  = (const float*)d_in[3];
    const float* b_hh  = (const float*)d_in[4];
    const float* w_lin = (const float*)d_in[5];
    const float* b_lin = (const float*)d_in[6];
    float* out = (float*)d_out;

    lstm_mfma<<<8192 / 32, NW * 64, 0, stream>>>(x, w_ih, w_hh, b_ih, b_hh,
                                                 w_lin, b_lin, out);
}

// Round 8
// 317.163 us; speedup vs baseline: 1.0898x; 1.0898x over previous
//
#include <hip/hip_runtime.h>
#include <hip/hip_bf16.h>

// LSTM B=8192,T=512,I=3,H=25 + linear[H->1], bf16 MFMA 16x16x32.
// R8: R7 measured the per-barrier-section chain at ~665cy but paid TWO
// sections per iteration (barrier between tile A and tile B serially coupled
// them). Fix: ONE barrier per step amortized over BOTH tiles — tile A and
// tile B computed back-to-back in a single region (independent chains ->
// intra-wave ILP), single __syncthreads. 256 blocks (1/CU) x 7 waves;
// wave w owns frag T=w for both tiles. Target ~330-400 cy/tile-step.
// x pre-packed bf16 in LDS, 2 chunks of 256 steps (64 KB, 1 mid-loop restage).

#define TSTEPS 512
#define ISZ 3
#define HSZ 25
#define NW 7
#define CHUNK 256
#define TSTRIDE 40          // shorts per batch row (80 B)

typedef __attribute__((ext_vector_type(8))) short bf16x8;
typedef __attribute__((ext_vector_type(4))) float f32x4;

__device__ __forceinline__ unsigned short bf16_bits(float v) {
    return __builtin_bit_cast(unsigned short, __float2bfloat16(v));
}
__device__ __forceinline__ unsigned int pack_bf16(float lo, float hi) {
    return ((unsigned int)bf16_bits(hi) << 16) | (unsigned int)bf16_bits(lo);
}

// 8-trans LSTM cell: c' = sig(a1)*c + sig(a0)*tanh(a2); h = sig(a3)*tanh(c')
__device__ __forceinline__ void lstm_act(const f32x4 acc, float& c, float& h) {
    const float K1 = 1.442695040888963f;   // log2 e
    const float K2 = 2.885390081777927f;   // 2 log2 e
    const float e0 = __builtin_amdgcn_exp2f(-K1 * acc[0]);
    const float e1 = __builtin_amdgcn_exp2f(-K1 * acc[1]);
    const float e2 = __builtin_amdgcn_exp2f(fminf(-K2 * acc[2], 126.0f));
    const float e3 = __builtin_amdgcn_exp2f(-K1 * acc[3]);
    const float f  = __builtin_amdgcn_rcpf(1.0f + e1);
    const float ig = (1.0f - e2) * __builtin_amdgcn_rcpf((1.0f + e0) * (1.0f + e2));
    c = fmaf(f, c, ig);
    const float ec = __builtin_amdgcn_exp2f(fminf(-K2 * c, 126.0f));
    h = (1.0f - ec) * __builtin_amdgcn_rcpf((1.0f + e3) * (1.0f + ec));
}

__global__ __launch_bounds__(NW * 64) void lstm_mfma(
    const float* __restrict__ x,      // [B, T, I]
    const float* __restrict__ w_ih,   // [4H, I]
    const float* __restrict__ w_hh,   // [4H, H]
    const float* __restrict__ b_ih,   // [4H]
    const float* __restrict__ b_hh,   // [4H]
    const float* __restrict__ w_lin,  // [1, H]
    const float* __restrict__ b_lin,  // [1]
    float* __restrict__ out)          // [B, 1]
{
    __shared__ uint2 xpk[2][CHUNK][16];       // 64 KB packed bf16 x (+1.0)
    __shared__ short hb[2][2][16 * TSTRIDE];  // [parity][tile] h rows, 5 KB
    __shared__ float outred[2][NW][16];

    const int tid  = threadIdx.x;
    const int w    = tid >> 6;       // wave 0..6: frag T=w (units 4w..4w+3)
    const int lane = tid & 63;
    const int n    = lane & 15;      // batch within tile
    const int q    = lane >> 4;      // quad -> unit u = 4w + q
    const bool isq0 = (q == 0);
    const int u    = 4 * w + q;
    const bool act = (w < 6) || isq0;          // u < 25

    // zero both h parity buffers, both tiles (pad slots stay 0 forever)
    for (int i = tid; i < 2 * 2 * 16 * TSTRIDE; i += NW * 64) ((short*)hb)[i] = 0;

    // ---- stage one 256-step chunk of x for both tiles (pre-packed bf16) ----
    auto stage = [&](int c0) {
        const int bsel = tid & 31;                 // batch in the 32-batch pair
        const int tile = bsel >> 4, nn = bsel & 15;
        const float* __restrict__ g =
            x + (size_t)(blockIdx.x * 32 + bsel) * (TSTEPS * ISZ) + c0 * ISZ;
        for (int tg = tid >> 5; tg < CHUNK / 4; tg += 14) {   // 4-step groups
            const float4* f4 = (const float4*)(g + tg * 12);
            float4 a = f4[0], b4 = f4[1], c4 = f4[2];
            const float s[4][3] = { {a.x, a.y, a.z}, {a.w, b4.x, b4.y},
                                    {b4.z, b4.w, c4.x}, {c4.y, c4.z, c4.w} };
            #pragma unroll
            for (int uu = 0; uu < 4; ++uu) {
                uint2 d;
                d.x = pack_bf16(s[uu][0], s[uu][1]);
                d.y = pack_bf16(s[uu][2], 1.0f);
                xpk[tile][tg * 4 + uu][nn] = d;
            }
        }
    };
    stage(0);

    // ---- this wave's A fragment (loaded once, register-resident) ----
    // A[r=16w+n][k=q*8+j]; row r=4u'+g (unit-major); k: [w_ih 0..2, bias 3, w_hh 4..28]
    bf16x8 afrag;
    #pragma unroll
    for (int j = 0; j < 8; ++j) {
        const int k = q * 8 + j;
        const int r = 16 * w + n;
        const int uu = r >> 2, g = r & 3;
        float v = 0.0f;
        if (uu < HSZ) {
            const int orow = g * HSZ + uu;         // original i,f,g,o row order
            if (k < ISZ)            v = w_ih[orow * ISZ + k];
            else if (k == ISZ)      v = b_ih[orow] + b_hh[orow];
            else if (k < 4 + HSZ)   v = w_hh[orow * HSZ + (k - 4)];
        }
        afrag[j] = (short)bf16_bits(v);
    }

    __syncthreads();

    float cA = 0.f, hA = 0.f, cB = 0.f, hB = 0.f;

    #pragma unroll 1
    for (int t = 0; t < TSTEPS; ++t) {
        if (t == CHUNK) {                 // entry synced by barrier of t-1
            stage(CHUNK);
            __syncthreads();
        }
        const int ts = t & (CHUNK - 1);
        const uint2 xA = xpk[0][ts][n];
        const uint2 xB = xpk[1][ts][n];
        // both tiles' h(t) visible since barrier(t-1): read both at loop top,
        // latencies overlap; chains below are independent (intra-wave ILP)
        bf16x8 bfA = *reinterpret_cast<const bf16x8*>(&hb[t & 1][0][n * TSTRIDE + q * 8]);
        bf16x8 bfB = *reinterpret_cast<const bf16x8*>(&hb[t & 1][1][n * TSTRIDE + q * 8]);

        uint4 biA = __builtin_bit_cast(uint4, bfA);
        uint4 biB = __builtin_bit_cast(uint4, bfB);
        if (isq0) {
            biA.x = xA.x; biA.y = xA.y;
            biB.x = xB.x; biB.y = xB.y;
        }
        const f32x4 accA = __builtin_amdgcn_mfma_f32_16x16x32_bf16(
            afrag, __builtin_bit_cast(bf16x8, biA),
            (f32x4){0.f, 0.f, 0.f, 0.f}, 0, 0, 0);
        const f32x4 accB = __builtin_amdgcn_mfma_f32_16x16x32_bf16(
            afrag, __builtin_bit_cast(bf16x8, biB),
            (f32x4){0.f, 0.f, 0.f, 0.f}, 0, 0, 0);

        lstm_act(accA, cA, hA);
        lstm_act(accB, cB, hB);

        if (act) {
            hb[(t + 1) & 1][0][n * TSTRIDE + 4 + u] = (short)bf16_bits(hA);
            hb[(t + 1) & 1][1][n * TSTRIDE + 4 + u] = (short)bf16_bits(hB);
        }
        __syncthreads();                  // ONE barrier per step, both tiles
    }

    // ---- final linear: out[b] = sum_u w_lin[u]*h[u] + b_lin ----
    float vA = 0.f, vB = 0.f;
    if (act) { vA = w_lin[u] * hA; vB = w_lin[u] * hB; }
    vA += __shfl_xor(vA, 16); vA += __shfl_xor(vA, 32);
    vB += __shfl_xor(vB, 16); vB += __shfl_xor(vB, 32);
    if (lane < 16) { outred[0][w][lane] = vA; outred[1][w][lane] = vB; }
    __syncthreads();
    if (tid < 32) {
        const int tile = tid >> 4, nn = tid & 15;
        float s = b_lin[0];
        #pragma unroll
        for (int k = 0; k < NW; ++k) s += outred[tile][k][nn];
        out[blockIdx.x * 32 + tile * 16 + nn] = s;
    }
}

extern "C" void kernel_launch(void* const* d_in, const int* in_sizes, int n_in,
                              void* d_out, int out_size, void* d_ws, size_t ws_size,
                              hipStream_t stream) {
    const float* x     = (const float*)d_in[0];
    const float* w_ih  = (const float*)d_in[1];
    const float* w_hh  = (const float*)d_in[2];
    const float* b_ih  = (const float*)d_in[3];
    const float* b_hh  = (const float*)d_in[4];
    const float* w_lin = (const float*)d_in[5];
    const float* b_lin = (const float*)d_in[6];
    float* out = (float*)d_out;

    lstm_mfma<<<8192 / 32, NW * 64, 0, stream>>>(x, w_ih, w_hh, b_ih, b_hh,
                                                 w_lin, b_lin, out);
}